// Round 18
// baseline (202.744 us; speedup 1.0000x reference)
//
#include <hip/hip_runtime.h>
#include <math.h>

#define NNODES 200000
#define NG 1000
#define NPG 200
#define KNN 5
#define MD 128
#define S6 (1.0f / 6.0f)

typedef _Float16 half8 __attribute__((ext_vector_type(8)));
typedef float floatx4 __attribute__((ext_vector_type(4)));

// fp16 Hs layout: value (row, col) at half-index row*128 + gswz(col>>3,row)*8 + (col&7)
// granule = 8 halves = 16 B (b128). 8 granules {0..7} (or {8..15}) cover all 32
// banks once regardless of row -> 8-lanes-per-row gathers conflict-free (R6 shape).
// XOR swizzle stays within each 8-granule block (in-place column-phase safety).
__device__ __forceinline__ int gswz(int gq, int row) {
  return (gq & 8) | ((gq & 7) ^ (row & 7));
}

// ---------------- merged pre-kernel ----------------
// blocks 0..999:     kNN — branchless scan (R11-validated, bit-identical compare
//                    semantics to the original branchy scan).
// blocks 1000..1199: embW0 = emb @ W0 (fp32), 4-way k-split + LDS reduce.
// blocks 1200..1215: W1/W2 prepack into f16 MFMA B-frag layout (single plane).
__global__ __launch_bounds__(256) void pre_kernel(
    const float* __restrict__ pos, const float* __restrict__ emb,
    const float* __restrict__ convW, int* __restrict__ knn,
    float* __restrict__ embW, _Float16* __restrict__ WF) {
  __shared__ float4 sp4[NPG];
  __shared__ float part[256];
  const int b = blockIdx.x;
  const int t = threadIdx.x;
  if (b < 1000) {
    const int g = b;
    if (t < NPG) {
      const float* p = pos + (size_t)g * NPG * 3 + (size_t)t * 3;
      sp4[t] = make_float4(p[0], p[1], p[2], 0.0f);
    }
    __syncthreads();
    if (t < NPG) {
      const float x = sp4[t].x, y = sp4[t].y, zz = sp4[t].z;
      float bd0 = 3.0e38f, bd1 = 3.0e38f, bd2 = 3.0e38f, bd3 = 3.0e38f,
            bd4 = 3.0e38f;
      int bi0 = 0, bi1 = 0, bi2 = 0, bi3 = 0, bi4 = 0;
#pragma unroll 4
      for (int j = 0; j < NPG; j++) {
        const float4 pj = sp4[j];  // uniform addr -> broadcast, conflict-free
        const float dx = __fsub_rn(x, pj.x);
        const float dy = __fsub_rn(y, pj.y);
        const float dz = __fsub_rn(zz, pj.z);
        float d2 = __fadd_rn(__fadd_rn(__fmul_rn(dx, dx), __fmul_rn(dy, dy)),
                             __fmul_rn(dz, dz));
        d2 = (j == t) ? 3.0e38f : d2;  // self never inserts (strict <)
        const bool c0 = d2 < bd0, c1 = d2 < bd1, c2 = d2 < bd2, c3 = d2 < bd3,
                   c4 = d2 < bd4;
        const float n0 = fminf(d2, bd0);
        const float n1 = fminf(fmaxf(d2, bd0), bd1);
        const float n2 = fminf(fmaxf(d2, bd1), bd2);
        const float n3 = fminf(fmaxf(d2, bd2), bd3);
        const float n4 = fminf(fmaxf(d2, bd3), bd4);
        const int m0 = c0 ? j : bi0;
        const int m1 = c1 ? (c0 ? bi0 : j) : bi1;
        const int m2 = c2 ? (c1 ? bi1 : j) : bi2;
        const int m3 = c3 ? (c2 ? bi2 : j) : bi3;
        const int m4 = c4 ? (c3 ? bi3 : j) : bi4;
        bd0 = n0; bd1 = n1; bd2 = n2; bd3 = n3; bd4 = n4;
        bi0 = m0; bi1 = m1; bi2 = m2; bi3 = m3; bi4 = m4;
      }
      int* kn = knn + ((size_t)g * NPG + t) * KNN;
      kn[0] = bi0; kn[1] = bi1; kn[2] = bi2; kn[3] = bi3; kn[4] = bi4;
    }
  } else if (b < 1200) {
    const int bb = b - 1000;
    const int o = bb * 64 + (t >> 2);  // output 0..12799
    const int r = o >> 7, c = o & 127;
    const int ks = t & 3;              // k-chunk 32*ks..+31
    const float* er = emb + (size_t)r * MD + 32 * ks;
    const float* wc = convW + c + (size_t)(32 * ks) * MD;
    float a = 0.0f;
#pragma unroll
    for (int k = 0; k < 32; k++) a += er[k] * wc[(size_t)k * MD];
    part[t] = a;
    __syncthreads();
    if (t < 64) {
      embW[bb * 64 + t] =
          part[4 * t] + part[4 * t + 1] + part[4 * t + 2] + part[4 * t + 3];
    }
  } else {
    const int idx = (b - 1200) * 256 + t;  // 0..4095
    const int lane = idx & 63;
    const int c = (idx >> 6) & 3;
    const int T = (idx >> 8) & 7;
    const int l = idx >> 11;  // 0..1 -> W1, W2
    const float* W = convW + (size_t)(l + 1) * MD * MD;
    const int m = lane & 15, q = lane >> 4;
    const int n = 16 * T + m;
    half8 hv;
#pragma unroll
    for (int j = 0; j < 8; j++) {
      const int k = 32 * c + 8 * q + j;
      hv[j] = (_Float16)W[(size_t)k * MD + n];  // RNE fp16
    }
    _Float16* out = WF + ((((size_t)l * 32) + T * 4 + c) * 64 + lane) * 8;
    *(half8*)out = hv;
  }
}

// ---------------- fused per-graph megakernel — fp16 h, 2 blocks/CU ----------------
// One block = one graph, 1024 threads (16 waves). LDS ~62 KB -> TWO blocks
// co-resident per CU (32 waves), independent barrier domains: one block's
// gather phase overlaps the other's VALU/MFMA (R16: 137.8 -> 95.9 us).
// R17: packed-fp16 tree agg (95.9 -> 80.3 us, absmax 1.22e-4 held).
// R18 change (single variable): agg granule-phases MERGED — all 32 granules
// read (24 gathers in flight/thread) before ONE barrier, then all written.
// res[2][2] half8 = 16 VGPRs across the barrier (R13-proven level; R14's
// fatal merge was 32 fp32 regs). Arithmetic bit-identical to R17 ->
// absmax must stay exactly 1.220703e-4. Go/no-go: VGPR<=64 (2-block
// residency), WRITE_SIZE ~31 KB (spill check).
__global__ __launch_bounds__(1024) void fused_kernel(
    const int* __restrict__ z, const int* __restrict__ knn,
    const float* __restrict__ embW, const float* __restrict__ convb,
    const _Float16* __restrict__ WF,
    const float* __restrict__ rW1, const float* __restrict__ rb1,
    const float* __restrict__ rW2, const float* __restrict__ rb2,
    const float* __restrict__ rW3, const float* __restrict__ rb3,
    float* __restrict__ out) {
  __shared__ _Float16 Hs[208 * MD];  // 53,248 B
  __shared__ int kl[NPG * KNN];      // 4,000 B
  __shared__ float red[8 * MD];      // 4,096 B
  __shared__ float pooled[MD];
  __shared__ float h1s[64];
  __shared__ float h2s[32];

  const int g = blockIdx.x;
  const int t = threadIdx.x;

  if (t < 250) ((int4*)kl)[t] = ((const int4*)(knn + (size_t)g * NPG * KNN))[t];

  const int rs = t >> 3;   // row slot 0..127 (8 lanes per row)
  const int g0 = t & 7;    // granule slot within 8-block
  __syncthreads();  // kl visible

  // ---- stage h0 = fp16(embW[z]) ----
#pragma unroll
  for (int ps = 0; ps < 2; ps++) {
    const int row = 128 * ps + rs;
    if (row < NPG) {
      const int zi = z[g * NPG + row];
      const float4* E = (const float4*)(embW + (size_t)zi * MD);
#pragma unroll
      for (int pp = 0; pp < 2; pp++) {
        const int gq = g0 + 8 * pp;
        const float4 e0 = E[2 * gq];
        const float4 e1 = E[2 * gq + 1];
        half8 hv;
        hv[0] = (_Float16)e0.x; hv[1] = (_Float16)e0.y;
        hv[2] = (_Float16)e0.z; hv[3] = (_Float16)e0.w;
        hv[4] = (_Float16)e1.x; hv[5] = (_Float16)e1.y;
        hv[6] = (_Float16)e1.z; hv[7] = (_Float16)e1.w;
        *(half8*)(Hs + row * MD + gswz(gq, row) * 8) = hv;
      }
    }
  }
  __syncthreads();

  const int lane = t & 63;
  const int wv = t >> 6;
  const int m = lane & 15;
  const int q = lane >> 4;
  const int cg = wv & 3;                      // col-pair group: tiles 2cg, 2cg+1
  const int rg = wv >> 2;                     // row group
  const int rt0 = rg == 0 ? 0 : 1 + 3 * rg;   // 0,4,7,10
  const int nrt = rg == 0 ? 4 : 3;            // 4/3/3/3 over 13 row-tiles

#pragma unroll 1
  for (int l = 0; l < 3; l++) {
    const float* bb = convb + l * MD;
    // ---- agg (packed fp16 tree) + bias + relu -> fp16 x, IN PLACE,
    //      SINGLE merged phase: read all 32 granules, one barrier, write all ----
    {
      half8 res[2][2];  // [pass][pp] — 16 regs live across ONE barrier
#pragma unroll
      for (int ps = 0; ps < 2; ps++) {
        const int row = 128 * ps + rs;
        if (row < NPG) {
          const int* kn = kl + row * KNN;
          const int i1 = kn[0], i2 = kn[1], i3 = kn[2], i4 = kn[3], i5 = kn[4];
#pragma unroll
          for (int pp = 0; pp < 2; pp++) {
            const int gq = g0 + 8 * pp;
            const half8 a0 = *(const half8*)(Hs + row * MD + gswz(gq, row) * 8);
            const half8 a1 = *(const half8*)(Hs + i1 * MD + gswz(gq, i1) * 8);
            const half8 a2 = *(const half8*)(Hs + i2 * MD + gswz(gq, i2) * 8);
            const half8 a3 = *(const half8*)(Hs + i3 * MD + gswz(gq, i3) * 8);
            const half8 a4 = *(const half8*)(Hs + i4 * MD + gswz(gq, i4) * 8);
            const half8 a5 = *(const half8*)(Hs + i5 * MD + gswz(gq, i5) * 8);
            // packed tree sum: 5 half8 adds (v_pk_add_f16), depth 3
            const half8 t01 = a0 + a1;
            const half8 t23 = a2 + a3;
            const half8 t45 = a4 + a5;
            const half8 sh = (t01 + t23) + t45;
            const float4 b0 = ((const float4*)bb)[2 * gq];
            const float4 b1 = ((const float4*)bb)[2 * gq + 1];
            half8 r;
#pragma unroll
            for (int e = 0; e < 4; e++)
              r[e] = (_Float16)fmaxf((float)sh[e] * S6 + ((const float*)&b0)[e], 0.0f);
#pragma unroll
            for (int e = 0; e < 4; e++)
              r[e + 4] = (_Float16)fmaxf((float)sh[e + 4] * S6 + ((const float*)&b1)[e], 0.0f);
            res[ps][pp] = r;
          }
        }
      }
      __syncthreads();  // ALL reads (both passes, both halves) done before writes
#pragma unroll
      for (int ps = 0; ps < 2; ps++) {
        const int row = 128 * ps + rs;
        if (row < NPG) {
#pragma unroll
          for (int pp = 0; pp < 2; pp++) {
            const int gq = g0 + 8 * pp;
            *(half8*)(Hs + row * MD + gswz(gq, row) * 8) = res[ps][pp];
          }
        }
      }
      __syncthreads();  // x visible
    }

    if (l < 2) {
      // ---- MFMA: h_{l+1} = x @ W_{l+1} (f16 single product, 4x4 split) ----
      const half8* WFl = (const half8*)WF + (size_t)l * 2048;
      floatx4 acc[2][4];
#pragma unroll
      for (int tt = 0; tt < 2; tt++)
#pragma unroll
        for (int i = 0; i < 4; i++) acc[tt][i] = (floatx4){0.f, 0.f, 0.f, 0.f};
#pragma unroll 1
      for (int c = 0; c < 4; c++) {
        const half8 b0 = WFl[((2 * cg) * 4 + c) * 64 + lane];
        const half8 b1 = WFl[((2 * cg + 1) * 4 + c) * 64 + lane];
        const int gk = 4 * c + q;  // A granule for k = 32c+8q..+7
#pragma unroll
        for (int i = 0; i < 4; i++) {
          if (i < nrt) {
            const int rowA = 16 * (rt0 + i) + m;  // rowA&7 == m&7
            // rows 200..207 read garbage: row-confined in MFMA, discarded
            const half8 a = *(const half8*)(Hs + rowA * MD + gswz(gk, rowA) * 8);
            acc[0][i] = __builtin_amdgcn_mfma_f32_16x16x32_f16(a, b0, acc[0][i], 0, 0, 0);
            acc[1][i] = __builtin_amdgcn_mfma_f32_16x16x32_f16(a, b1, acc[1][i], 0, 0, 0);
          }
        }
      }
      __syncthreads();  // all x frag reads done before overwrite

      // ---- write-back h_{l+1} as fp16 ----
#pragma unroll
      for (int tt = 0; tt < 2; tt++) {
        const int col = 16 * (2 * cg + tt) + m;
        const int gq2 = col >> 3;
        const int e2 = col & 7;
#pragma unroll
        for (int i = 0; i < 4; i++) {
          if (i < nrt) {
#pragma unroll
            for (int reg = 0; reg < 4; reg++) {
              const int row = 16 * (rt0 + i) + 4 * q + reg;
              if (row < NPG)
                Hs[row * MD + gswz(gq2, row) * 8 + e2] = (_Float16)acc[tt][i][reg];
            }
          }
        }
      }
      __syncthreads();
    }
  }

  // ---- mean pool: 8 row-groups x 128 cols ----
  {
    const int col = t & 127;
    const int j = t >> 7;  // 0..7, rows j*25..j*25+24
    const int gq = col >> 3, e = col & 7;
    float s = 0.f;
    for (int i = 0; i < 25; i++) {
      const int row = j * 25 + i;
      s += (float)Hs[row * MD + gswz(gq, row) * 8 + e];
    }
    red[j * MD + col] = s;
  }
  __syncthreads();
  if (t < MD) {
    float p = 0.f;
#pragma unroll
    for (int j = 0; j < 8; j++) p += red[j * MD + t];
    pooled[t] = p * (1.0f / (float)NPG);
  }
  __syncthreads();

  // ---- regressor MLP ----
  if (t < 64) {
    float a = rb1[t];
    for (int c = 0; c < 128; c++) a += pooled[c] * rW1[c * 64 + t];
    h1s[t] = fmaxf(a, 0.0f);
  }
  __syncthreads();
  if (t < 32) {
    float a = rb2[t];
    for (int c = 0; c < 64; c++) a += h1s[c] * rW2[c * 32 + t];
    h2s[t] = fmaxf(a, 0.0f);
  }
  __syncthreads();
  if (t == 0) {
    float a = rb3[0];
    for (int c = 0; c < 32; c++) a += h2s[c] * rW3[c];
    out[g] = a;
  }
}

extern "C" void kernel_launch(void* const* d_in, const int* in_sizes, int n_in,
                              void* d_out, int out_size, void* d_ws, size_t ws_size,
                              hipStream_t stream) {
  const int* z = (const int*)d_in[0];
  const float* pos = (const float*)d_in[1];
  const float* emb = (const float*)d_in[3];
  const float* convW = (const float*)d_in[4];  // [3][128][128]
  const float* convb = (const float*)d_in[5];  // [3][128]
  const float* rW1 = (const float*)d_in[6];
  const float* rb1 = (const float*)d_in[7];
  const float* rW2 = (const float*)d_in[8];
  const float* rb2 = (const float*)d_in[9];
  const float* rW3 = (const float*)d_in[10];
  const float* rb3 = (const float*)d_in[11];
  float* out = (float*)d_out;

  char* ws = (char*)d_ws;
  int* knn = (int*)ws;                                  // 4,000,000 B
  float* embW = (float*)(ws + 4000000);                 // 51,200 B
  _Float16* WF = (_Float16*)(ws + 4051200);             // 65,536 B (W1,W2 f16 frags)

  pre_kernel<<<1216, 256, 0, stream>>>(pos, emb, convW, knn, embW, WF);
  fused_kernel<<<NG, 1024, 0, stream>>>(z, knn, embW, convb, WF,
                                        rW1, rb1, rW2, rb2, rW3, rb3, out);
}

// Round 19
// 194.795 us; speedup vs baseline: 1.0408x; 1.0408x over previous
//
#include <hip/hip_runtime.h>
#include <math.h>

#define NNODES 200000
#define NG 1000
#define NPG 200
#define KNN 5
#define MD 128
#define S6 (1.0f / 6.0f)

typedef _Float16 half8 __attribute__((ext_vector_type(8)));
typedef float floatx4 __attribute__((ext_vector_type(4)));

// fp16 Hs layout: value (row, col) at half-index row*128 + gswz(col>>3,row)*8 + (col&7)
// granule = 8 halves = 16 B (b128). 8 granules {0..7} (or {8..15}) cover all 32
// banks once regardless of row -> 8-lanes-per-row gathers conflict-free (R6 shape).
// XOR swizzle stays within each 8-granule block (in-place column-phase safety).
__device__ __forceinline__ int gswz(int gq, int row) {
  return (gq & 8) | ((gq & 7) ^ (row & 7));
}

// ---------------- merged pre-kernel ----------------
// blocks 0..999:     kNN — branchless scan (R11-validated, bit-identical compare
//                    semantics to the original branchy scan).
// blocks 1000..1199: embW0 = emb @ W0 (fp32), 4-way k-split + LDS reduce.
// blocks 1200..1215: W1/W2 prepack into f16 MFMA B-frag layout (single plane).
__global__ __launch_bounds__(256) void pre_kernel(
    const float* __restrict__ pos, const float* __restrict__ emb,
    const float* __restrict__ convW, int* __restrict__ knn,
    float* __restrict__ embW, _Float16* __restrict__ WF) {
  __shared__ float4 sp4[NPG];
  __shared__ float part[256];
  const int b = blockIdx.x;
  const int t = threadIdx.x;
  if (b < 1000) {
    const int g = b;
    if (t < NPG) {
      const float* p = pos + (size_t)g * NPG * 3 + (size_t)t * 3;
      sp4[t] = make_float4(p[0], p[1], p[2], 0.0f);
    }
    __syncthreads();
    if (t < NPG) {
      const float x = sp4[t].x, y = sp4[t].y, zz = sp4[t].z;
      float bd0 = 3.0e38f, bd1 = 3.0e38f, bd2 = 3.0e38f, bd3 = 3.0e38f,
            bd4 = 3.0e38f;
      int bi0 = 0, bi1 = 0, bi2 = 0, bi3 = 0, bi4 = 0;
#pragma unroll 4
      for (int j = 0; j < NPG; j++) {
        const float4 pj = sp4[j];  // uniform addr -> broadcast, conflict-free
        const float dx = __fsub_rn(x, pj.x);
        const float dy = __fsub_rn(y, pj.y);
        const float dz = __fsub_rn(zz, pj.z);
        float d2 = __fadd_rn(__fadd_rn(__fmul_rn(dx, dx), __fmul_rn(dy, dy)),
                             __fmul_rn(dz, dz));
        d2 = (j == t) ? 3.0e38f : d2;  // self never inserts (strict <)
        const bool c0 = d2 < bd0, c1 = d2 < bd1, c2 = d2 < bd2, c3 = d2 < bd3,
                   c4 = d2 < bd4;
        const float n0 = fminf(d2, bd0);
        const float n1 = fminf(fmaxf(d2, bd0), bd1);
        const float n2 = fminf(fmaxf(d2, bd1), bd2);
        const float n3 = fminf(fmaxf(d2, bd2), bd3);
        const float n4 = fminf(fmaxf(d2, bd3), bd4);
        const int m0 = c0 ? j : bi0;
        const int m1 = c1 ? (c0 ? bi0 : j) : bi1;
        const int m2 = c2 ? (c1 ? bi1 : j) : bi2;
        const int m3 = c3 ? (c2 ? bi2 : j) : bi3;
        const int m4 = c4 ? (c3 ? bi3 : j) : bi4;
        bd0 = n0; bd1 = n1; bd2 = n2; bd3 = n3; bd4 = n4;
        bi0 = m0; bi1 = m1; bi2 = m2; bi3 = m3; bi4 = m4;
      }
      int* kn = knn + ((size_t)g * NPG + t) * KNN;
      kn[0] = bi0; kn[1] = bi1; kn[2] = bi2; kn[3] = bi3; kn[4] = bi4;
    }
  } else if (b < 1200) {
    const int bb = b - 1000;
    const int o = bb * 64 + (t >> 2);  // output 0..12799
    const int r = o >> 7, c = o & 127;
    const int ks = t & 3;              // k-chunk 32*ks..+31
    const float* er = emb + (size_t)r * MD + 32 * ks;
    const float* wc = convW + c + (size_t)(32 * ks) * MD;
    float a = 0.0f;
#pragma unroll
    for (int k = 0; k < 32; k++) a += er[k] * wc[(size_t)k * MD];
    part[t] = a;
    __syncthreads();
    if (t < 64) {
      embW[bb * 64 + t] =
          part[4 * t] + part[4 * t + 1] + part[4 * t + 2] + part[4 * t + 3];
    }
  } else {
    const int idx = (b - 1200) * 256 + t;  // 0..4095
    const int lane = idx & 63;
    const int c = (idx >> 6) & 3;
    const int T = (idx >> 8) & 7;
    const int l = idx >> 11;  // 0..1 -> W1, W2
    const float* W = convW + (size_t)(l + 1) * MD * MD;
    const int m = lane & 15, q = lane >> 4;
    const int n = 16 * T + m;
    half8 hv;
#pragma unroll
    for (int j = 0; j < 8; j++) {
      const int k = 32 * c + 8 * q + j;
      hv[j] = (_Float16)W[(size_t)k * MD + n];  // RNE fp16
    }
    _Float16* out = WF + ((((size_t)l * 32) + T * 4 + c) * 64 + lane) * 8;
    *(half8*)out = hv;
  }
}

// ---------------- fused per-graph megakernel — R17 VERBATIM (session best) ----------------
// One block = one graph, 1024 threads (16 waves). LDS ~62 KB -> TWO blocks
// co-resident per CU (32 waves), independent barrier domains: one block's
// gather phase overlaps the other's VALU/MFMA (R16: 137.8 -> 95.9 us).
// R17: packed-fp16 tree agg (95.9 -> 80.3 us, absmax 1.22e-4 held).
// R18 lesson: merging the two granule-phases (16 extra regs across a barrier)
// pushed VGPR 52 -> 64 cap and spilled 27 MB — the phase split below is the
// max that fits the allocator's envelope. Iron law: 7 spill incidents, all at
// >~55 live regs.
__global__ __launch_bounds__(1024) void fused_kernel(
    const int* __restrict__ z, const int* __restrict__ knn,
    const float* __restrict__ embW, const float* __restrict__ convb,
    const _Float16* __restrict__ WF,
    const float* __restrict__ rW1, const float* __restrict__ rb1,
    const float* __restrict__ rW2, const float* __restrict__ rb2,
    const float* __restrict__ rW3, const float* __restrict__ rb3,
    float* __restrict__ out) {
  __shared__ _Float16 Hs[208 * MD];  // 53,248 B
  __shared__ int kl[NPG * KNN];      // 4,000 B
  __shared__ float red[8 * MD];      // 4,096 B
  __shared__ float pooled[MD];
  __shared__ float h1s[64];
  __shared__ float h2s[32];

  const int g = blockIdx.x;
  const int t = threadIdx.x;

  if (t < 250) ((int4*)kl)[t] = ((const int4*)(knn + (size_t)g * NPG * KNN))[t];

  const int rs = t >> 3;   // row slot 0..127 (8 lanes per row)
  const int g0 = t & 7;    // granule slot within 8-block
  __syncthreads();  // kl visible

  // ---- stage h0 = fp16(embW[z]) ----
#pragma unroll
  for (int ps = 0; ps < 2; ps++) {
    const int row = 128 * ps + rs;
    if (row < NPG) {
      const int zi = z[g * NPG + row];
      const float4* E = (const float4*)(embW + (size_t)zi * MD);
#pragma unroll
      for (int pp = 0; pp < 2; pp++) {
        const int gq = g0 + 8 * pp;
        const float4 e0 = E[2 * gq];
        const float4 e1 = E[2 * gq + 1];
        half8 hv;
        hv[0] = (_Float16)e0.x; hv[1] = (_Float16)e0.y;
        hv[2] = (_Float16)e0.z; hv[3] = (_Float16)e0.w;
        hv[4] = (_Float16)e1.x; hv[5] = (_Float16)e1.y;
        hv[6] = (_Float16)e1.z; hv[7] = (_Float16)e1.w;
        *(half8*)(Hs + row * MD + gswz(gq, row) * 8) = hv;
      }
    }
  }
  __syncthreads();

  const int lane = t & 63;
  const int wv = t >> 6;
  const int m = lane & 15;
  const int q = lane >> 4;
  const int cg = wv & 3;                      // col-pair group: tiles 2cg, 2cg+1
  const int rg = wv >> 2;                     // row group
  const int rt0 = rg == 0 ? 0 : 1 + 3 * rg;   // 0,4,7,10
  const int nrt = rg == 0 ? 4 : 3;            // 4/3/3/3 over 13 row-tiles

#pragma unroll 1
  for (int l = 0; l < 3; l++) {
    const float* bb = convb + l * MD;
    // ---- agg (packed fp16 tree) + bias + relu -> fp16 x, IN PLACE ----
#pragma unroll 1
    for (int ph = 0; ph < 2; ph++) {
      const int gq = 8 * ph + g0;
      half8 res[2];  // 8 regs live across ONE barrier
#pragma unroll
      for (int ps = 0; ps < 2; ps++) {
        const int row = 128 * ps + rs;
        if (row < NPG) {
          const int* kn = kl + row * KNN;
          const int i1 = kn[0], i2 = kn[1], i3 = kn[2], i4 = kn[3], i5 = kn[4];
          const half8 a0 = *(const half8*)(Hs + row * MD + gswz(gq, row) * 8);
          const half8 a1 = *(const half8*)(Hs + i1 * MD + gswz(gq, i1) * 8);
          const half8 a2 = *(const half8*)(Hs + i2 * MD + gswz(gq, i2) * 8);
          const half8 a3 = *(const half8*)(Hs + i3 * MD + gswz(gq, i3) * 8);
          const half8 a4 = *(const half8*)(Hs + i4 * MD + gswz(gq, i4) * 8);
          const half8 a5 = *(const half8*)(Hs + i5 * MD + gswz(gq, i5) * 8);
          // packed tree sum: 5 half8 adds (v_pk_add_f16), depth 3
          const half8 t01 = a0 + a1;
          const half8 t23 = a2 + a3;
          const half8 t45 = a4 + a5;
          const half8 sh = (t01 + t23) + t45;
          const float4 b0 = ((const float4*)bb)[2 * gq];
          const float4 b1 = ((const float4*)bb)[2 * gq + 1];
          half8 r;
#pragma unroll
          for (int e = 0; e < 4; e++)
            r[e] = (_Float16)fmaxf((float)sh[e] * S6 + ((const float*)&b0)[e], 0.0f);
#pragma unroll
          for (int e = 0; e < 4; e++)
            r[e + 4] = (_Float16)fmaxf((float)sh[e + 4] * S6 + ((const float*)&b1)[e], 0.0f);
          res[ps] = r;
        }
      }
      __syncthreads();  // ALL reads (both passes) done before in-place writes
#pragma unroll
      for (int ps = 0; ps < 2; ps++) {
        const int row = 128 * ps + rs;
        if (row < NPG)
          *(half8*)(Hs + row * MD + gswz(gq, row) * 8) = res[ps];
      }
      __syncthreads();  // x visible
    }

    if (l < 2) {
      // ---- MFMA: h_{l+1} = x @ W_{l+1} (f16 single product, 4x4 split) ----
      const half8* WFl = (const half8*)WF + (size_t)l * 2048;
      floatx4 acc[2][4];
#pragma unroll
      for (int tt = 0; tt < 2; tt++)
#pragma unroll
        for (int i = 0; i < 4; i++) acc[tt][i] = (floatx4){0.f, 0.f, 0.f, 0.f};
#pragma unroll 1
      for (int c = 0; c < 4; c++) {
        const half8 b0 = WFl[((2 * cg) * 4 + c) * 64 + lane];
        const half8 b1 = WFl[((2 * cg + 1) * 4 + c) * 64 + lane];
        const int gk = 4 * c + q;  // A granule for k = 32c+8q..+7
#pragma unroll
        for (int i = 0; i < 4; i++) {
          if (i < nrt) {
            const int rowA = 16 * (rt0 + i) + m;  // rowA&7 == m&7
            // rows 200..207 read garbage: row-confined in MFMA, discarded
            const half8 a = *(const half8*)(Hs + rowA * MD + gswz(gk, rowA) * 8);
            acc[0][i] = __builtin_amdgcn_mfma_f32_16x16x32_f16(a, b0, acc[0][i], 0, 0, 0);
            acc[1][i] = __builtin_amdgcn_mfma_f32_16x16x32_f16(a, b1, acc[1][i], 0, 0, 0);
          }
        }
      }
      __syncthreads();  // all x frag reads done before overwrite

      // ---- write-back h_{l+1} as fp16 ----
#pragma unroll
      for (int tt = 0; tt < 2; tt++) {
        const int col = 16 * (2 * cg + tt) + m;
        const int gq2 = col >> 3;
        const int e2 = col & 7;
#pragma unroll
        for (int i = 0; i < 4; i++) {
          if (i < nrt) {
#pragma unroll
            for (int reg = 0; reg < 4; reg++) {
              const int row = 16 * (rt0 + i) + 4 * q + reg;
              if (row < NPG)
                Hs[row * MD + gswz(gq2, row) * 8 + e2] = (_Float16)acc[tt][i][reg];
            }
          }
        }
      }
      __syncthreads();
    }
  }

  // ---- mean pool: 8 row-groups x 128 cols ----
  {
    const int col = t & 127;
    const int j = t >> 7;  // 0..7, rows j*25..j*25+24
    const int gq = col >> 3, e = col & 7;
    float s = 0.f;
    for (int i = 0; i < 25; i++) {
      const int row = j * 25 + i;
      s += (float)Hs[row * MD + gswz(gq, row) * 8 + e];
    }
    red[j * MD + col] = s;
  }
  __syncthreads();
  if (t < MD) {
    float p = 0.f;
#pragma unroll
    for (int j = 0; j < 8; j++) p += red[j * MD + t];
    pooled[t] = p * (1.0f / (float)NPG);
  }
  __syncthreads();

  // ---- regressor MLP ----
  if (t < 64) {
    float a = rb1[t];
    for (int c = 0; c < 128; c++) a += pooled[c] * rW1[c * 64 + t];
    h1s[t] = fmaxf(a, 0.0f);
  }
  __syncthreads();
  if (t < 32) {
    float a = rb2[t];
    for (int c = 0; c < 64; c++) a += h1s[c] * rW2[c * 32 + t];
    h2s[t] = fmaxf(a, 0.0f);
  }
  __syncthreads();
  if (t == 0) {
    float a = rb3[0];
    for (int c = 0; c < 32; c++) a += h2s[c] * rW3[c];
    out[g] = a;
  }
}

extern "C" void kernel_launch(void* const* d_in, const int* in_sizes, int n_in,
                              void* d_out, int out_size, void* d_ws, size_t ws_size,
                              hipStream_t stream) {
  const int* z = (const int*)d_in[0];
  const float* pos = (const float*)d_in[1];
  const float* emb = (const float*)d_in[3];
  const float* convW = (const float*)d_in[4];  // [3][128][128]
  const float* convb = (const float*)d_in[5];  // [3][128]
  const float* rW1 = (const float*)d_in[6];
  const float* rb1 = (const float*)d_in[7];
  const float* rW2 = (const float*)d_in[8];
  const float* rb2 = (const float*)d_in[9];
  const float* rW3 = (const float*)d_in[10];
  const float* rb3 = (const float*)d_in[11];
  float* out = (float*)d_out;

  char* ws = (char*)d_ws;
  int* knn = (int*)ws;                                  // 4,000,000 B
  float* embW = (float*)(ws + 4000000);                 // 51,200 B
  _Float16* WF = (_Float16*)(ws + 4051200);             // 65,536 B (W1,W2 f16 frags)

  pre_kernel<<<1216, 256, 0, stream>>>(pos, emb, convW, knn, embW, WF);
  fused_kernel<<<NG, 1024, 0, stream>>>(z, knn, embW, convb, WF,
                                        rW1, rb1, rW2, rb2, rW3, rb3, out);
}